// Round 1
// baseline (5739.441 us; speedup 1.0000x reference)
//
#include <hip/hip_runtime.h>
#include <hip/hip_bf16.h>

// Problem dims (fixed by reference)
#define ND 50000
#define NP 20000
#define ED 65536
#define EP 65536
#define BB 4096
#define EPS 1e-5f

// ---------------- SGEMM: C[M,N] = A[M,K] @ B[K,N] (+bias) (+leaky) ----------------
#define BM 64
#define BN 64
#define BK 16

__global__ __launch_bounds__(256) void sgemm(const float* __restrict__ A,
                                             const float* __restrict__ B,
                                             const float* __restrict__ bias,
                                             float* __restrict__ C,
                                             int M, int N, int K, int applyLeaky) {
    __shared__ float As[BK][BM + 4];
    __shared__ float Bs[BK][BN + 4];
    const int tid = threadIdx.x;
    const int tx = tid & 15;       // 0..15 (N micro)
    const int ty = tid >> 4;       // 0..15 (M micro)
    const int row0 = blockIdx.y * BM;
    const int col0 = blockIdx.x * BN;

    float acc[4][4] = {};

    for (int k0 = 0; k0 < K; k0 += BK) {
        // Load A tile (BM x BK): 256 threads x 4
        #pragma unroll
        for (int i = 0; i < 4; i++) {
            int m = (tid >> 4) + i * 16;   // 0..63
            int k = tid & 15;              // 0..15
            float v = 0.f;
            int gm = row0 + m, gk = k0 + k;
            if (gm < M && gk < K) v = A[(size_t)gm * K + gk];
            As[k][m] = v;
        }
        // Load B tile (BK x BN): 256 threads x 4
        #pragma unroll
        for (int i = 0; i < 4; i++) {
            int k = (tid >> 6) + i * 4;    // 0..15
            int n = tid & 63;              // 0..63
            float v = 0.f;
            int gk = k0 + k, gn = col0 + n;
            if (gk < K && gn < N) v = B[(size_t)gk * N + gn];
            Bs[k][n] = v;
        }
        __syncthreads();
        #pragma unroll
        for (int k = 0; k < BK; k++) {
            float4 a = *(const float4*)&As[k][ty * 4];
            float4 b = *(const float4*)&Bs[k][tx * 4];
            float ar[4] = {a.x, a.y, a.z, a.w};
            float br[4] = {b.x, b.y, b.z, b.w};
            #pragma unroll
            for (int i = 0; i < 4; i++)
                #pragma unroll
                for (int j = 0; j < 4; j++)
                    acc[i][j] = fmaf(ar[i], br[j], acc[i][j]);
        }
        __syncthreads();
    }

    #pragma unroll
    for (int i = 0; i < 4; i++) {
        int m = row0 + ty * 4 + i;
        if (m >= M) continue;
        #pragma unroll
        for (int j = 0; j < 4; j++) {
            int n = col0 + tx * 4 + j;
            if (n >= N) continue;
            float v = acc[i][j];
            if (bias) v += bias[n];
            if (applyLeaky) v = (v >= 0.f) ? v : 0.01f * v;
            C[(size_t)m * N + n] = v;
        }
    }
}

// ---------------- GCN helpers ----------------
__global__ void deg_kernel(const int* __restrict__ dst, const float* __restrict__ w,
                           float* __restrict__ deg, int E) {
    int e = blockIdx.x * blockDim.x + threadIdx.x;
    if (e < E) atomicAdd(&deg[dst[e]], w[e]);
}

__global__ void dis_kernel(const float* __restrict__ deg, float* __restrict__ dis, int N) {
    int n = blockIdx.x * blockDim.x + threadIdx.x;
    if (n < N) dis[n] = rsqrtf(deg[n] + 1.0f);  // deg includes implicit +1 self-loop, always > 0
}

__global__ void claim_kernel(const int* __restrict__ idx, int* __restrict__ map, int Bn) {
    int i = blockIdx.x * blockDim.x + threadIdx.x;
    if (i < Bn) atomicCAS(&map[idx[i]], -1, i);
}

// One block per edge; only edges whose dst is a selected node contribute.
__global__ void scatter_kernel(const int* __restrict__ src, const int* __restrict__ dst,
                               const float* __restrict__ w, const float* __restrict__ dis,
                               const int* __restrict__ map, const float* __restrict__ H,
                               float* __restrict__ compact, int F) {
    int e = blockIdx.x;
    int d = dst[e];
    int slot = map[d];
    if (slot < 0) return;
    int s = src[e];
    float norm = dis[s] * w[e] * dis[d];
    const float* hrow = H + (size_t)s * F;
    float* crow = compact + (size_t)slot * F;
    for (int f = threadIdx.x; f < F; f += blockDim.x)
        atomicAdd(&crow[f], norm * hrow[f]);
}

// Per batch row: add self-loop + bias, leaky, write into feature slab column range.
__global__ void gather_kernel(const int* __restrict__ index, const int* __restrict__ map,
                              const float* __restrict__ dis, const float* __restrict__ H,
                              const float* __restrict__ compact, const float* __restrict__ bias,
                              float* __restrict__ feature, int F, int ldF, int colOff) {
    int i = blockIdx.x;
    int n = index[i];
    int slot = map[n];
    float d2 = dis[n] * dis[n];
    const float* hrow = H + (size_t)n * F;
    const float* crow = compact + (size_t)slot * F;
    float* out = feature + (size_t)i * ldF + colOff;
    for (int f = threadIdx.x; f < F; f += blockDim.x) {
        float v = crow[f] + d2 * hrow[f] + bias[f];
        out[f] = (v >= 0.f) ? v : 0.01f * v;
    }
}

__global__ void copy_cols(const float* __restrict__ X, float* __restrict__ Fout,
                          int Bn, int C, int ldF, int colOff) {
    size_t i = (size_t)blockIdx.x * blockDim.x + threadIdx.x;
    if (i >= (size_t)Bn * C) return;
    int r = (int)(i / C), c = (int)(i % C);
    Fout[(size_t)r * ldF + colOff + c] = X[i];
}

// ---------------- BatchNorm (training mode, biased var) ----------------
__global__ void bn_stats(const float* __restrict__ X, float* __restrict__ stats,
                         int Bn, int C, int rowsPerBlock) {
    int c = blockIdx.x * blockDim.x + threadIdx.x;
    if (c >= C) return;
    int r0 = blockIdx.y * rowsPerBlock;
    int r1 = min(r0 + rowsPerBlock, Bn);
    float s1 = 0.f, s2 = 0.f;
    for (int r = r0; r < r1; r++) {
        float v = X[(size_t)r * C + c];
        s1 += v;
        s2 += v * v;
    }
    atomicAdd(&stats[c], s1);
    atomicAdd(&stats[C + c], s2);
}

__global__ void bn_apply(const float* __restrict__ X, const float* __restrict__ stats,
                         const float* __restrict__ gamma, const float* __restrict__ beta,
                         float* __restrict__ Y, int Bn, int C, int leakyAfter) {
    size_t i = (size_t)blockIdx.x * blockDim.x + threadIdx.x;
    if (i >= (size_t)Bn * C) return;
    int c = (int)(i % C);
    float m = stats[c] / (float)Bn;
    float v = stats[C + c] / (float)Bn - m * m;
    float xn = (X[i] - m) * rsqrtf(v + EPS) * gamma[c] + beta[c];
    if (leakyAfter) xn = (xn >= 0.f) ? xn : 0.01f * xn;
    Y[i] = xn;
}

// ---------------- final y = o @ W_o2 + b ----------------
__global__ void rowdot_kernel(const float* __restrict__ X, const float* __restrict__ Wv,
                              const float* __restrict__ b, float* __restrict__ y,
                              int Bn, int K) {
    int row = blockIdx.x * (blockDim.x >> 6) + (threadIdx.x >> 6);
    int lane = threadIdx.x & 63;
    if (row >= Bn) return;
    float s = 0.f;
    for (int k = lane; k < K; k += 64) s += X[(size_t)row * K + k] * Wv[k];
    #pragma unroll
    for (int off = 32; off > 0; off >>= 1) s += __shfl_down(s, off);
    if (lane == 0) y[row] = s + b[0];
}

// ---------------- launch ----------------
extern "C" void kernel_launch(void* const* d_in, const int* in_sizes, int n_in,
                              void* d_out, int out_size, void* d_ws, size_t ws_size,
                              hipStream_t stream) {
    const int*   d_index = (const int*)d_in[0];
    const int*   p_index = (const int*)d_in[1];
    const float* d_vecs  = (const float*)d_in[2];
    const float* p_emb   = (const float*)d_in[3];
    const float* d_ecfps = (const float*)d_in[4];
    const int*   d_eidx  = (const int*)d_in[5];   // [0:ED]=src, [ED:2ED]=dst
    const float* d_ew    = (const float*)d_in[6];
    const float* p_gos   = (const float*)d_in[7];
    const int*   p_eidx  = (const int*)d_in[8];
    const float* p_ew    = (const float*)d_in[9];
    const float* W_dg = (const float*)d_in[10];
    const float* b_dg = (const float*)d_in[11];
    const float* W_pg = (const float*)d_in[12];
    const float* b_pg = (const float*)d_in[13];
    const float* W_e1 = (const float*)d_in[14];
    const float* b_e1 = (const float*)d_in[15];
    const float* g_e1 = (const float*)d_in[16];
    const float* be_e1= (const float*)d_in[17];
    const float* W_e2 = (const float*)d_in[18];
    const float* b_e2 = (const float*)d_in[19];
    const float* g_e2 = (const float*)d_in[20];
    const float* be_e2= (const float*)d_in[21];
    const float* W_o1 = (const float*)d_in[22];
    const float* b_o1 = (const float*)d_in[23];
    const float* g_o  = (const float*)d_in[24];
    const float* be_o = (const float*)d_in[25];
    const float* W_o2 = (const float*)d_in[26];
    const float* b_o2 = (const float*)d_in[27];

    // workspace layout (floats)
    float* ws = (float*)d_ws;
    size_t o = 0;
    float* H       = ws + o; o += (size_t)ND * 1024;      // reused for Hp
    float* compact = ws + o; o += (size_t)BB * 1024;
    float* deg     = ws + o; o += ND;
    float* dis     = ws + o; o += ND;
    int*   map     = (int*)(ws + o); o += ND;
    float* feature = ws + o; o += (size_t)BB * 3372;
    float* Z1      = ws + o; o += (size_t)BB * 2048;
    float* Z3      = ws + o; o += (size_t)BB * 256;
    float* stats   = ws + o; o += 4096;

    float* y     = (float*)d_out;            // [4096]
    float* feat2 = (float*)d_out + BB;       // [4096,1024]

    dim3 blk256(256);

    // ============ drug branch ============
    hipMemsetAsync(deg, 0, ND * sizeof(float), stream);
    hipMemsetAsync(map, 0xFF, ND * sizeof(int), stream);
    hipMemsetAsync(compact, 0, (size_t)BB * 1024 * sizeof(float), stream);

    {   // Hd = d_ecfps @ W_dg
        dim3 g(1024 / BN, (ND + BM - 1) / BM);
        sgemm<<<g, blk256, 0, stream>>>(d_ecfps, W_dg, nullptr, H, ND, 1024, 1024, 0);
    }
    deg_kernel<<<dim3((ED + 255) / 256), blk256, 0, stream>>>(d_eidx + ED, d_ew, deg, ED);
    dis_kernel<<<dim3((ND + 255) / 256), blk256, 0, stream>>>(deg, dis, ND);
    claim_kernel<<<dim3((BB + 255) / 256), blk256, 0, stream>>>(d_index, map, BB);
    scatter_kernel<<<dim3(ED), blk256, 0, stream>>>(d_eidx, d_eidx + ED, d_ew, dis, map, H, compact, 1024);
    gather_kernel<<<dim3(BB), blk256, 0, stream>>>(d_index, map, dis, H, compact, b_dg,
                                                   feature, 1024, 3372, 1324);

    // ============ protein branch ============
    hipMemsetAsync(deg, 0, NP * sizeof(float), stream);
    hipMemsetAsync(map, 0xFF, NP * sizeof(int), stream);
    hipMemsetAsync(compact, 0, (size_t)BB * 1024 * sizeof(float), stream);

    {   // Hp = p_gos @ W_pg
        dim3 g(1024 / BN, (NP + BM - 1) / BM);
        sgemm<<<g, blk256, 0, stream>>>(p_gos, W_pg, nullptr, H, NP, 1024, 2812, 0);
    }
    deg_kernel<<<dim3((EP + 255) / 256), blk256, 0, stream>>>(p_eidx + EP, p_ew, deg, EP);
    dis_kernel<<<dim3((NP + 255) / 256), blk256, 0, stream>>>(deg, dis, NP);
    claim_kernel<<<dim3((BB + 255) / 256), blk256, 0, stream>>>(p_index, map, BB);
    scatter_kernel<<<dim3(EP), blk256, 0, stream>>>(p_eidx, p_eidx + EP, p_ew, dis, map, H, compact, 1024);
    gather_kernel<<<dim3(BB), blk256, 0, stream>>>(p_index, map, dis, H, compact, b_pg,
                                                   feature, 1024, 3372, 2348);

    // ============ concat the dense inputs ============
    copy_cols<<<dim3((BB * 300 + 255) / 256), blk256, 0, stream>>>(d_vecs, feature, BB, 300, 3372, 0);
    copy_cols<<<dim3((BB * 1024 + 255) / 256), blk256, 0, stream>>>(p_emb, feature, BB, 1024, 3372, 300);

    // ============ encoder layer 1: Z1 = feature @ W_e1 + b_e1; BN; leaky ============
    {
        dim3 g(2048 / BN, BB / BM);
        sgemm<<<g, blk256, 0, stream>>>(feature, W_e1, b_e1, Z1, BB, 2048, 3372, 0);
    }
    hipMemsetAsync(stats, 0, 2 * 2048 * sizeof(float), stream);
    bn_stats<<<dim3(2048 / 256, BB / 256), blk256, 0, stream>>>(Z1, stats, BB, 2048, 256);
    bn_apply<<<dim3((BB * 2048 + 255) / 256), blk256, 0, stream>>>(Z1, stats, g_e1, be_e1, Z1, BB, 2048, 1);

    // ============ encoder layer 2: Z2 = Z1 @ W_e2 + b_e2; BN; leaky -> feat2 (output) ============
    {
        dim3 g(1024 / BN, BB / BM);
        sgemm<<<g, blk256, 0, stream>>>(Z1, W_e2, b_e2, compact, BB, 1024, 2048, 0);  // compact reused as Z2
    }
    hipMemsetAsync(stats, 0, 2 * 1024 * sizeof(float), stream);
    bn_stats<<<dim3(1024 / 256, BB / 256), blk256, 0, stream>>>(compact, stats, BB, 1024, 256);
    bn_apply<<<dim3((BB * 1024 + 255) / 256), blk256, 0, stream>>>(compact, stats, g_e2, be_e2, feat2, BB, 1024, 1);

    // ============ output head: Z3 = leaky(feat2 @ W_o1 + b_o1); BN; y = o @ W_o2 + b_o2 ============
    {
        dim3 g(256 / BN, BB / BM);
        sgemm<<<g, blk256, 0, stream>>>(feat2, W_o1, b_o1, Z3, BB, 256, 1024, 1);
    }
    hipMemsetAsync(stats, 0, 2 * 256 * sizeof(float), stream);
    bn_stats<<<dim3(256 / 256, BB / 256), blk256, 0, stream>>>(Z3, stats, BB, 256, 256);
    bn_apply<<<dim3((BB * 256 + 255) / 256), blk256, 0, stream>>>(Z3, stats, g_o, be_o, Z3, BB, 256, 0);

    rowdot_kernel<<<dim3(BB / 4), blk256, 0, stream>>>(Z3, W_o2, b_o2, y, BB, 256);
}

// Round 2
// 1590.416 us; speedup vs baseline: 3.6088x; 3.6088x over previous
//
#include <hip/hip_runtime.h>
#include <hip/hip_bf16.h>

// Problem dims (fixed by reference)
#define ND 50000
#define NP 20000
#define ED 65536
#define EP 65536
#define BB 4096
#define EPS 1e-5f

// padded dims
#define ND_P 50048      // 391*128
#define NP_P 20096      // 157*128
#define KP_P 2816       // 2812 -> 88*32
#define KF_P 3392       // 3372 -> 106*32
#define LDF  3392

typedef __bf16 bf16_t;
typedef __bf16 bf16x8 __attribute__((ext_vector_type(8)));
typedef float f32x4 __attribute__((ext_vector_type(4)));

// ======================= bf16 MFMA GEMM (m97 structure) =======================
// C[M,N] = A[M,K] @ B[K,N], with A [M,K] bf16 row-major (lda=K) and
// Bt [N,K] bf16 row-major (B transposed, ldb=K). M%128==0, N%128==0, K%32==0.
// Epilogue: optional bias (indexed by col), optional leaky, store fp32 and/or bf16.

__device__ __forceinline__ void load_lds16(const bf16_t* g, bf16_t* l) {
    __builtin_amdgcn_global_load_lds(
        (const __attribute__((address_space(1))) unsigned int*)g,
        (__attribute__((address_space(3))) unsigned int*)l,
        16, 0, 0);
}

__global__ __launch_bounds__(256) void gemm_bf16(
    const bf16_t* __restrict__ A, const bf16_t* __restrict__ Bt,
    float* __restrict__ Cf, bf16_t* __restrict__ Cb,
    const float* __restrict__ bias,
    int M, int N, int K, int leaky)
{
    __shared__ __align__(16) bf16_t As[128][32];
    __shared__ __align__(16) bf16_t Bs[128][32];
    const int tid = threadIdx.x;
    const int wave = tid >> 6, lane = tid & 63;
    const int quad = lane >> 4, r16 = lane & 15;
    const int wm = (wave >> 1) * 64, wn = (wave & 1) * 64;
    const int row0 = blockIdx.y * 128, col0 = blockIdx.x * 128;

    f32x4 acc[4][4] = {};

    // staging: thread t covers row (t>>2) and 16B k-segment (t&3); second issue adds 64 rows.
    const bf16_t* aBase = A + (size_t)(row0 + (tid >> 2)) * K + (tid & 3) * 8;
    const bf16_t* bBase = Bt + (size_t)(col0 + (tid >> 2)) * K + (tid & 3) * 8;
    bf16_t* lA = &As[0][0] + tid * 8;
    bf16_t* lB = &Bs[0][0] + tid * 8;
    const size_t rowStep = (size_t)64 * K;

    for (int k0 = 0; k0 < K; k0 += 32) {
        load_lds16(aBase + k0, lA);
        load_lds16(aBase + k0 + rowStep, lA + 2048);
        load_lds16(bBase + k0, lB);
        load_lds16(bBase + k0 + rowStep, lB + 2048);
        __syncthreads();
        bf16x8 af[4], bfr[4];
        #pragma unroll
        for (int i = 0; i < 4; i++)
            af[i] = *(const bf16x8*)&As[wm + i * 16 + r16][quad * 8];
        #pragma unroll
        for (int j = 0; j < 4; j++)
            bfr[j] = *(const bf16x8*)&Bs[wn + j * 16 + r16][quad * 8];
        #pragma unroll
        for (int i = 0; i < 4; i++)
            #pragma unroll
            for (int j = 0; j < 4; j++)
                acc[i][j] = __builtin_amdgcn_mfma_f32_16x16x32_bf16(af[i], bfr[j], acc[i][j], 0, 0, 0);
        __syncthreads();
    }

    #pragma unroll
    for (int i = 0; i < 4; i++) {
        int rowb = row0 + wm + i * 16 + quad * 4;
        #pragma unroll
        for (int j = 0; j < 4; j++) {
            int col = col0 + wn + j * 16 + r16;
            float bv = bias ? bias[col] : 0.f;
            #pragma unroll
            for (int rg = 0; rg < 4; rg++) {
                float v = acc[i][j][rg] + bv;
                if (leaky) v = (v >= 0.f) ? v : 0.01f * v;
                size_t off = (size_t)(rowb + rg) * N + col;
                if (Cf) Cf[off] = v;
                if (Cb) Cb[off] = (bf16_t)v;
            }
        }
    }
}

// ======================= conversion / transpose =======================
__global__ void convert_pad(const float* __restrict__ X, bf16_t* __restrict__ Y,
                            int M, int K, int Kp, size_t total) {
    size_t i = (size_t)blockIdx.x * blockDim.x + threadIdx.x;
    if (i >= total) return;
    int r = (int)(i / Kp), c = (int)(i % Kp);
    float v = (r < M && c < K) ? X[(size_t)r * K + c] : 0.f;
    Y[i] = (bf16_t)v;
}

// W [K,N] fp32 -> Wt [N,Kp] bf16 (zero-pad K..Kp)
__global__ void transpose_convert(const float* __restrict__ W, bf16_t* __restrict__ Wt,
                                  int K, int N, int Kp) {
    __shared__ float t[32][33];
    int kb = blockIdx.y * 32, nb = blockIdx.x * 32;
    int tx = threadIdx.x & 31, ty = threadIdx.x >> 5;   // 32x8
    #pragma unroll
    for (int dy = 0; dy < 32; dy += 8) {
        int k = kb + ty + dy, n = nb + tx;
        t[ty + dy][tx] = (k < K && n < N) ? W[(size_t)k * N + n] : 0.f;
    }
    __syncthreads();
    #pragma unroll
    for (int dy = 0; dy < 32; dy += 8) {
        int n = nb + ty + dy, k = kb + tx;
        if (n < N && k < Kp) Wt[(size_t)n * Kp + k] = (bf16_t)t[tx][ty + dy];
    }
}

// ======================= GCN helpers =======================
__global__ void deg_kernel(const int* __restrict__ dst, const float* __restrict__ w,
                           float* __restrict__ deg, int E) {
    int e = blockIdx.x * blockDim.x + threadIdx.x;
    if (e < E) atomicAdd(&deg[dst[e]], w[e]);
}

__global__ void dis_kernel(const float* __restrict__ deg, float* __restrict__ dis, int N) {
    int n = blockIdx.x * blockDim.x + threadIdx.x;
    if (n < N) dis[n] = rsqrtf(deg[n] + 1.0f);
}

__global__ void claim_kernel(const int* __restrict__ idx, int* __restrict__ map, int Bn) {
    int i = blockIdx.x * blockDim.x + threadIdx.x;
    if (i < Bn) atomicCAS(&map[idx[i]], -1, i);
}

__global__ void scatter_kernel(const int* __restrict__ src, const int* __restrict__ dst,
                               const float* __restrict__ w, const float* __restrict__ dis,
                               const int* __restrict__ map, const bf16_t* __restrict__ H,
                               float* __restrict__ compact) {
    int e = blockIdx.x;
    int d = dst[e];
    int slot = map[d];
    if (slot < 0) return;
    int s = src[e];
    float norm = dis[s] * w[e] * dis[d];
    const bf16_t* hrow = H + (size_t)s * 1024;
    float* crow = compact + (size_t)slot * 1024;
    for (int f = threadIdx.x; f < 1024; f += blockDim.x)
        atomicAdd(&crow[f], norm * (float)hrow[f]);
}

__global__ void gather_kernel(const int* __restrict__ index, const int* __restrict__ map,
                              const float* __restrict__ dis, const bf16_t* __restrict__ H,
                              const float* __restrict__ compact, const float* __restrict__ bias,
                              bf16_t* __restrict__ featb, int colOff) {
    int i = blockIdx.x;
    int n = index[i];
    int slot = map[n];
    float d2 = dis[n] * dis[n];
    const bf16_t* hrow = H + (size_t)n * 1024;
    const float* crow = compact + (size_t)slot * 1024;
    bf16_t* out = featb + (size_t)i * LDF + colOff;
    for (int f = threadIdx.x; f < 1024; f += blockDim.x) {
        float v = crow[f] + d2 * (float)hrow[f] + bias[f];
        out[f] = (bf16_t)((v >= 0.f) ? v : 0.01f * v);
    }
}

__global__ void copy_cols_b(const float* __restrict__ X, bf16_t* __restrict__ featb,
                            int C, int colOff, size_t total) {
    size_t i = (size_t)blockIdx.x * blockDim.x + threadIdx.x;
    if (i >= total) return;
    int r = (int)(i / C), c = (int)(i % C);
    featb[(size_t)r * LDF + colOff + c] = (bf16_t)X[i];
}

// ======================= BatchNorm (training mode) =======================
__global__ void bn_stats(const float* __restrict__ X, float* __restrict__ stats,
                         int C, int rowsPerBlock) {
    int c = blockIdx.x * blockDim.x + threadIdx.x;
    if (c >= C) return;
    int r0 = blockIdx.y * rowsPerBlock;
    int r1 = r0 + rowsPerBlock;
    float s1 = 0.f, s2 = 0.f;
    for (int r = r0; r < r1; r++) {
        float v = X[(size_t)r * C + c];
        s1 += v;
        s2 += v * v;
    }
    atomicAdd(&stats[c], s1);
    atomicAdd(&stats[C + c], s2);
}

__global__ void bn_apply(const float* __restrict__ X, const float* __restrict__ stats,
                         const float* __restrict__ gamma, const float* __restrict__ beta,
                         float* __restrict__ Yf, bf16_t* __restrict__ Yb,
                         int C, int leaky, size_t total) {
    size_t i = (size_t)blockIdx.x * blockDim.x + threadIdx.x;
    if (i >= total) return;
    int c = (int)(i % C);
    float m = stats[c] * (1.f / BB);
    float v = stats[C + c] * (1.f / BB) - m * m;
    float xn = (X[i] - m) * rsqrtf(v + EPS) * gamma[c] + beta[c];
    if (leaky) xn = (xn >= 0.f) ? xn : 0.01f * xn;
    if (Yf) Yf[i] = xn;
    if (Yb) Yb[i] = (bf16_t)xn;
}

// ======================= final y = o @ W_o2 + b =======================
__global__ void rowdot_kernel(const float* __restrict__ X, const float* __restrict__ Wv,
                              const float* __restrict__ b, float* __restrict__ y, int K) {
    int row = blockIdx.x * (blockDim.x >> 6) + (threadIdx.x >> 6);
    int lane = threadIdx.x & 63;
    if (row >= BB) return;
    float s = 0.f;
    for (int k = lane; k < K; k += 64) s += X[(size_t)row * K + k] * Wv[k];
    #pragma unroll
    for (int off = 32; off > 0; off >>= 1) s += __shfl_down(s, off);
    if (lane == 0) y[row] = s + b[0];
}

// ======================= launch =======================
extern "C" void kernel_launch(void* const* d_in, const int* in_sizes, int n_in,
                              void* d_out, int out_size, void* d_ws, size_t ws_size,
                              hipStream_t stream) {
    const int*   d_index = (const int*)d_in[0];
    const int*   p_index = (const int*)d_in[1];
    const float* d_vecs  = (const float*)d_in[2];
    const float* p_emb   = (const float*)d_in[3];
    const float* d_ecfps = (const float*)d_in[4];
    const int*   d_eidx  = (const int*)d_in[5];
    const float* d_ew    = (const float*)d_in[6];
    const float* p_gos   = (const float*)d_in[7];
    const int*   p_eidx  = (const int*)d_in[8];
    const float* p_ew    = (const float*)d_in[9];
    const float* W_dg = (const float*)d_in[10];
    const float* b_dg = (const float*)d_in[11];
    const float* W_pg = (const float*)d_in[12];
    const float* b_pg = (const float*)d_in[13];
    const float* W_e1 = (const float*)d_in[14];
    // b_e1 (d_in[15]) cancels under BN (shift-invariance per column)
    const float* g_e1 = (const float*)d_in[16];
    const float* be_e1= (const float*)d_in[17];
    const float* W_e2 = (const float*)d_in[18];
    // b_e2 (d_in[19]) cancels under BN
    const float* g_e2 = (const float*)d_in[20];
    const float* be_e2= (const float*)d_in[21];
    const float* W_o1 = (const float*)d_in[22];
    const float* b_o1 = (const float*)d_in[23];   // pre-leaky: must apply
    const float* g_o  = (const float*)d_in[24];
    const float* be_o = (const float*)d_in[25];
    const float* W_o2 = (const float*)d_in[26];
    const float* b_o2 = (const float*)d_in[27];

    // ---- workspace layout (bytes) ----
    char* w = (char*)d_ws;
    bf16_t* H      = (bf16_t*)w; w += (size_t)ND_P * 1024 * 2;      // 102,498,304
    char*   regA   = w;          w += (size_t)NP_P * KP_P * 2;      // 113,180,672 (A bf16 / Z chain)
    float*  compact= (float*)w;  w += (size_t)BB * 1024 * 4;        // 16,777,216 (later feat2b)
    bf16_t* featb  = (bf16_t*)w; w += (size_t)BB * LDF * 2;         // 27,787,264
    bf16_t* Wt_dg  = (bf16_t*)w; w += (size_t)1024 * 1024 * 2;
    bf16_t* Wt_pg  = (bf16_t*)w; w += (size_t)1024 * KP_P * 2;
    bf16_t* Wt_e1  = (bf16_t*)w; w += (size_t)2048 * KF_P * 2;
    bf16_t* Wt_e2  = (bf16_t*)w; w += (size_t)1024 * 2048 * 2;
    bf16_t* Wt_o1  = (bf16_t*)w; w += (size_t)256 * 1024 * 2;
    float*  deg    = (float*)w;  w += (size_t)ND_P * 4;
    float*  dis    = (float*)w;  w += (size_t)ND_P * 4;
    int*    map    = (int*)w;    w += (size_t)ND_P * 4;
    float*  stats  = (float*)w;  w += 16384;

    // region A overlays (sequential lifetimes)
    bf16_t* Abf = (bf16_t*)regA;
    float*  Z1  = (float*)regA;                                 // 4096x2048 f32
    bf16_t* Z1b = (bf16_t*)(regA + 33554432);                   // 4096x2048 bf16
    float*  Z2  = (float*)(regA + 33554432 + 16777216);         // 4096x1024 f32
    float*  Z3  = (float*)(regA + 67108864);                    // 4096x256 f32
    float*  Z3n = (float*)(regA + 71303168);                    // 4096x256 f32
    bf16_t* feat2b = (bf16_t*)compact;                          // 4096x1024 bf16 (after gathers)

    float* y     = (float*)d_out;
    float* feat2 = (float*)d_out + BB;

    dim3 blk256(256);

    // ---- weight transposes (independent) ----
    transpose_convert<<<dim3(1024/32, 1024/32), blk256, 0, stream>>>(W_dg, Wt_dg, 1024, 1024, 1024);
    transpose_convert<<<dim3(1024/32, KP_P/32), blk256, 0, stream>>>(W_pg, Wt_pg, 2812, 1024, KP_P);
    transpose_convert<<<dim3(2048/32, KF_P/32), blk256, 0, stream>>>(W_e1, Wt_e1, 3372, 2048, KF_P);
    transpose_convert<<<dim3(1024/32, 2048/32), blk256, 0, stream>>>(W_e2, Wt_e2, 2048, 1024, 2048);
    transpose_convert<<<dim3(256/32, 1024/32), blk256, 0, stream>>>(W_o1, Wt_o1, 1024, 256, 1024);

    // ============ drug branch ============
    hipMemsetAsync(deg, 0, ND * sizeof(float), stream);
    hipMemsetAsync(map, 0xFF, ND * sizeof(int), stream);
    hipMemsetAsync(compact, 0, (size_t)BB * 1024 * sizeof(float), stream);

    {
        size_t tot = (size_t)ND_P * 1024;
        convert_pad<<<dim3((tot + 255) / 256), blk256, 0, stream>>>(d_ecfps, Abf, ND, 1024, 1024, tot);
        gemm_bf16<<<dim3(1024/128, ND_P/128), blk256, 0, stream>>>(Abf, Wt_dg, nullptr, H, nullptr,
                                                                   ND_P, 1024, 1024, 0);
    }
    deg_kernel<<<dim3((ED + 255) / 256), blk256, 0, stream>>>(d_eidx + ED, d_ew, deg, ED);
    dis_kernel<<<dim3((ND + 255) / 256), blk256, 0, stream>>>(deg, dis, ND);
    claim_kernel<<<dim3((BB + 255) / 256), blk256, 0, stream>>>(d_index, map, BB);
    scatter_kernel<<<dim3(ED), blk256, 0, stream>>>(d_eidx, d_eidx + ED, d_ew, dis, map, H, compact);
    gather_kernel<<<dim3(BB), blk256, 0, stream>>>(d_index, map, dis, H, compact, b_dg, featb, 1324);

    // ============ protein branch ============
    hipMemsetAsync(deg, 0, NP * sizeof(float), stream);
    hipMemsetAsync(map, 0xFF, NP * sizeof(int), stream);
    hipMemsetAsync(compact, 0, (size_t)BB * 1024 * sizeof(float), stream);

    {
        size_t tot = (size_t)NP_P * KP_P;
        convert_pad<<<dim3((tot + 255) / 256), blk256, 0, stream>>>(p_gos, Abf, NP, 2812, KP_P, tot);
        gemm_bf16<<<dim3(1024/128, NP_P/128), blk256, 0, stream>>>(Abf, Wt_pg, nullptr, H, nullptr,
                                                                   NP_P, 1024, KP_P, 0);
    }
    deg_kernel<<<dim3((EP + 255) / 256), blk256, 0, stream>>>(p_eidx + EP, p_ew, deg, EP);
    dis_kernel<<<dim3((NP + 255) / 256), blk256, 0, stream>>>(deg, dis, NP);
    claim_kernel<<<dim3((BB + 255) / 256), blk256, 0, stream>>>(p_index, map, BB);
    scatter_kernel<<<dim3(EP), blk256, 0, stream>>>(p_eidx, p_eidx + EP, p_ew, dis, map, H, compact);
    gather_kernel<<<dim3(BB), blk256, 0, stream>>>(p_index, map, dis, H, compact, b_pg, featb, 2348);

    // ============ dense concat ============
    {
        size_t t1 = (size_t)BB * 300, t2 = (size_t)BB * 1024;
        copy_cols_b<<<dim3((t1 + 255) / 256), blk256, 0, stream>>>(d_vecs, featb, 300, 0, t1);
        copy_cols_b<<<dim3((t2 + 255) / 256), blk256, 0, stream>>>(p_emb, featb, 1024, 300, t2);
    }

    // ============ e1: Z1 = featb @ W_e1 (bias cancels in BN); BN+leaky -> Z1b ============
    gemm_bf16<<<dim3(2048/128, BB/128), blk256, 0, stream>>>(featb, Wt_e1, Z1, nullptr, nullptr,
                                                             BB, 2048, KF_P, 0);
    hipMemsetAsync(stats, 0, 2 * 2048 * sizeof(float), stream);
    bn_stats<<<dim3(2048/256, BB/256), blk256, 0, stream>>>(Z1, stats, 2048, 256);
    bn_apply<<<dim3(((size_t)BB*2048 + 255) / 256), blk256, 0, stream>>>(Z1, stats, g_e1, be_e1,
                                                                          nullptr, Z1b, 2048, 1, (size_t)BB*2048);

    // ============ e2: Z2 = Z1b @ W_e2; BN+leaky -> feat2 (f32 out) + feat2b (bf16) ============
    gemm_bf16<<<dim3(1024/128, BB/128), blk256, 0, stream>>>(Z1b, Wt_e2, Z2, nullptr, nullptr,
                                                             BB, 1024, 2048, 0);
    hipMemsetAsync(stats, 0, 2 * 1024 * sizeof(float), stream);
    bn_stats<<<dim3(1024/256, BB/256), blk256, 0, stream>>>(Z2, stats, 1024, 256);
    bn_apply<<<dim3(((size_t)BB*1024 + 255) / 256), blk256, 0, stream>>>(Z2, stats, g_e2, be_e2,
                                                                          feat2, feat2b, 1024, 1, (size_t)BB*1024);

    // ============ o1: Z3 = leaky(feat2b @ W_o1 + b_o1); BN -> Z3n; y ============
    gemm_bf16<<<dim3(256/128, BB/128), blk256, 0, stream>>>(feat2b, Wt_o1, Z3, nullptr, b_o1,
                                                            BB, 256, 1024, 1);
    hipMemsetAsync(stats, 0, 2 * 256 * sizeof(float), stream);
    bn_stats<<<dim3(1, BB/256), blk256, 0, stream>>>(Z3, stats, 256, 256);
    bn_apply<<<dim3(((size_t)BB*256 + 255) / 256), blk256, 0, stream>>>(Z3, stats, g_o, be_o,
                                                                         Z3n, nullptr, 256, 0, (size_t)BB*256);
    rowdot_kernel<<<dim3(BB/4), blk256, 0, stream>>>(Z3n, W_o2, b_o2, y, 256);
}

// Round 3
// 1283.158 us; speedup vs baseline: 4.4729x; 1.2395x over previous
//
#include <hip/hip_runtime.h>
#include <hip/hip_bf16.h>

// Problem dims (fixed by reference)
#define ND 50000
#define NP 20000
#define ED 65536
#define EP 65536
#define BB 4096
#define EPS 1e-5f

// padded dims
#define KP_P 2816       // 2812 -> 88*32
#define KF_P 3392       // 3372 -> 106*32
#define LDF  3392

typedef __bf16 bf16_t;
typedef __bf16 bf16x8 __attribute__((ext_vector_type(8)));
typedef float f32x4 __attribute__((ext_vector_type(4)));

// ======================= bf16 MFMA GEMM (m97 structure) =======================
// C = A[M,K] @ Bt[N,K]^T. M%128==0, N%128==0, K%32==0, K*2 % 16 == 0.
// Epilogue: optional bias[col], optional leaky; writes to Cf (f32, ldcf) and/or Cb (bf16, ldcb).

__device__ __forceinline__ void load_lds16(const bf16_t* g, bf16_t* l) {
    __builtin_amdgcn_global_load_lds(
        (const __attribute__((address_space(1))) unsigned int*)g,
        (__attribute__((address_space(3))) unsigned int*)l,
        16, 0, 0);
}

__global__ __launch_bounds__(256) void gemm_bf16(
    const bf16_t* __restrict__ A, const bf16_t* __restrict__ Bt,
    float* __restrict__ Cf, int ldcf,
    bf16_t* __restrict__ Cb, int ldcb,
    const float* __restrict__ bias,
    int M, int N, int K, int leaky)
{
    __shared__ __align__(16) bf16_t As[128][32];
    __shared__ __align__(16) bf16_t Bs[128][32];
    const int tid = threadIdx.x;
    const int wave = tid >> 6, lane = tid & 63;
    const int quad = lane >> 4, r16 = lane & 15;
    const int wm = (wave >> 1) * 64, wn = (wave & 1) * 64;
    const int row0 = blockIdx.y * 128, col0 = blockIdx.x * 128;

    f32x4 acc[4][4] = {};

    const bf16_t* aBase = A + (size_t)(row0 + (tid >> 2)) * K + (tid & 3) * 8;
    const bf16_t* bBase = Bt + (size_t)(col0 + (tid >> 2)) * K + (tid & 3) * 8;
    bf16_t* lA = &As[0][0] + tid * 8;
    bf16_t* lB = &Bs[0][0] + tid * 8;
    const size_t rowStep = (size_t)64 * K;

    for (int k0 = 0; k0 < K; k0 += 32) {
        load_lds16(aBase + k0, lA);
        load_lds16(aBase + k0 + rowStep, lA + 2048);
        load_lds16(bBase + k0, lB);
        load_lds16(bBase + k0 + rowStep, lB + 2048);
        __syncthreads();
        bf16x8 af[4], bfr[4];
        #pragma unroll
        for (int i = 0; i < 4; i++)
            af[i] = *(const bf16x8*)&As[wm + i * 16 + r16][quad * 8];
        #pragma unroll
        for (int j = 0; j < 4; j++)
            bfr[j] = *(const bf16x8*)&Bs[wn + j * 16 + r16][quad * 8];
        #pragma unroll
        for (int i = 0; i < 4; i++)
            #pragma unroll
            for (int j = 0; j < 4; j++)
                acc[i][j] = __builtin_amdgcn_mfma_f32_16x16x32_bf16(af[i], bfr[j], acc[i][j], 0, 0, 0);
        __syncthreads();
    }

    #pragma unroll
    for (int i = 0; i < 4; i++) {
        int rowb = row0 + wm + i * 16 + quad * 4;
        #pragma unroll
        for (int j = 0; j < 4; j++) {
            int col = col0 + wn + j * 16 + r16;
            float bv = bias ? bias[col] : 0.f;
            #pragma unroll
            for (int rg = 0; rg < 4; rg++) {
                float v = acc[i][j][rg] + bv;
                if (leaky) v = (v >= 0.f) ? v : 0.01f * v;
                int row = rowb + rg;
                if (Cf) Cf[(size_t)row * ldcf + col] = v;
                if (Cb) Cb[(size_t)row * ldcb + col] = (bf16_t)v;
            }
        }
    }
}

// ======================= conversion / transpose =======================
__global__ void convert_pad(const float* __restrict__ X, bf16_t* __restrict__ Y,
                            int M, int K, int Kp, size_t total) {
    size_t i = (size_t)blockIdx.x * blockDim.x + threadIdx.x;
    if (i >= total) return;
    int r = (int)(i / Kp), c = (int)(i % Kp);
    float v = (r < M && c < K) ? X[(size_t)r * K + c] : 0.f;
    Y[i] = (bf16_t)v;
}

// W [K,N] fp32 -> Wt [N,Kp] bf16 (zero-pad K..Kp)
__global__ void transpose_convert(const float* __restrict__ W, bf16_t* __restrict__ Wt,
                                  int K, int N, int Kp) {
    __shared__ float t[32][33];
    int kb = blockIdx.y * 32, nb = blockIdx.x * 32;
    int tx = threadIdx.x & 31, ty = threadIdx.x >> 5;   // 32x8
    #pragma unroll
    for (int dy = 0; dy < 32; dy += 8) {
        int k = kb + ty + dy, n = nb + tx;
        t[ty + dy][tx] = (k < K && n < N) ? W[(size_t)k * N + n] : 0.f;
    }
    __syncthreads();
    #pragma unroll
    for (int dy = 0; dy < 32; dy += 8) {
        int n = nb + ty + dy, k = kb + tx;
        if (n < N && k < Kp) Wt[(size_t)n * Kp + k] = (bf16_t)t[tx][ty + dy];
    }
}

// ======================= GCN (input-space aggregation) =======================
__global__ void deg_kernel(const int* __restrict__ dst, const float* __restrict__ w,
                           float* __restrict__ deg, int E) {
    int e = blockIdx.x * blockDim.x + threadIdx.x;
    if (e < E) atomicAdd(&deg[dst[e]], w[e]);
}

__global__ void dis_kernel(const float* __restrict__ deg, float* __restrict__ dis, int N) {
    int n = blockIdx.x * blockDim.x + threadIdx.x;
    if (n < N) dis[n] = rsqrtf(deg[n] + 1.0f);
}

__global__ void claim_kernel(const int* __restrict__ idx, int* __restrict__ map, int Bn) {
    int i = blockIdx.x * blockDim.x + threadIdx.x;
    if (i < Bn) atomicCAS(&map[idx[i]], -1, i);
}

// Per-edge: if dst is a selected node, agg[slot] += norm * A_in[src]  (input space, fp32)
__global__ void scatter_in(const int* __restrict__ src, const int* __restrict__ dst,
                           const float* __restrict__ w, const float* __restrict__ dis,
                           const int* __restrict__ map, const float* __restrict__ A,
                           float* __restrict__ agg, int F) {
    int e = blockIdx.x;
    int d = dst[e];
    int slot = map[d];
    if (slot < 0) return;
    int s = src[e];
    float norm = dis[s] * w[e] * dis[d];
    const float* arow = A + (size_t)s * F;
    float* grow = agg + (size_t)slot * F;
    for (int f = threadIdx.x; f < F; f += blockDim.x)
        atomicAdd(&grow[f], norm * arow[f]);
}

// Self-loop term, winners only: agg[i] += dis[n]^2 * A_in[n]
__global__ void self_add(const int* __restrict__ idx, const int* __restrict__ map,
                         const float* __restrict__ dis, const float* __restrict__ A,
                         float* __restrict__ agg, int F) {
    int i = blockIdx.x;
    int n = idx[i];
    if (map[n] != i) return;
    float d2 = dis[n] * dis[n];
    const float* arow = A + (size_t)n * F;
    float* grow = agg + (size_t)i * F;
    for (int f = threadIdx.x; f < F; f += blockDim.x)
        grow[f] += d2 * arow[f];
}

// Duplicate batch indices: copy winner's GCN output row into dup rows.
__global__ void fix_dups(const int* __restrict__ idx, const int* __restrict__ map,
                         bf16_t* __restrict__ featb, int colOff) {
    int i = blockIdx.x;
    int s = map[idx[i]];
    if (s == i) return;
    bf16_t* dstp = featb + (size_t)i * LDF + colOff;
    const bf16_t* srcp = featb + (size_t)s * LDF + colOff;
    for (int f = threadIdx.x; f < 1024; f += blockDim.x)
        dstp[f] = srcp[f];
}

__global__ void copy_cols_b(const float* __restrict__ X, bf16_t* __restrict__ featb,
                            int C, int colOff, size_t total) {
    size_t i = (size_t)blockIdx.x * blockDim.x + threadIdx.x;
    if (i >= total) return;
    int r = (int)(i / C), c = (int)(i % C);
    featb[(size_t)r * LDF + colOff + c] = (bf16_t)X[i];
}

// ======================= BatchNorm (training mode) =======================
__global__ void bn_stats(const float* __restrict__ X, float* __restrict__ stats,
                         int C, int rowsPerBlock) {
    int c = blockIdx.x * blockDim.x + threadIdx.x;
    if (c >= C) return;
    int r0 = blockIdx.y * rowsPerBlock;
    int r1 = r0 + rowsPerBlock;
    float s1 = 0.f, s2 = 0.f;
    for (int r = r0; r < r1; r++) {
        float v = X[(size_t)r * C + c];
        s1 += v;
        s2 += v * v;
    }
    atomicAdd(&stats[c], s1);
    atomicAdd(&stats[C + c], s2);
}

__global__ void bn_apply(const float* __restrict__ X, const float* __restrict__ stats,
                         const float* __restrict__ gamma, const float* __restrict__ beta,
                         float* __restrict__ Yf, bf16_t* __restrict__ Yb,
                         int C, int leaky, size_t total) {
    size_t i = (size_t)blockIdx.x * blockDim.x + threadIdx.x;
    if (i >= total) return;
    int c = (int)(i % C);
    float m = stats[c] * (1.f / BB);
    float v = stats[C + c] * (1.f / BB) - m * m;
    float xn = (X[i] - m) * rsqrtf(v + EPS) * gamma[c] + beta[c];
    if (leaky) xn = (xn >= 0.f) ? xn : 0.01f * xn;
    if (Yf) Yf[i] = xn;
    if (Yb) Yb[i] = (bf16_t)xn;
}

// ======================= final y = o @ W_o2 + b =======================
__global__ void rowdot_kernel(const float* __restrict__ X, const float* __restrict__ Wv,
                              const float* __restrict__ b, float* __restrict__ y, int K) {
    int row = blockIdx.x * (blockDim.x >> 6) + (threadIdx.x >> 6);
    int lane = threadIdx.x & 63;
    if (row >= BB) return;
    float s = 0.f;
    for (int k = lane; k < K; k += 64) s += X[(size_t)row * K + k] * Wv[k];
    #pragma unroll
    for (int off = 32; off > 0; off >>= 1) s += __shfl_down(s, off);
    if (lane == 0) y[row] = s + b[0];
}

// ======================= launch =======================
extern "C" void kernel_launch(void* const* d_in, const int* in_sizes, int n_in,
                              void* d_out, int out_size, void* d_ws, size_t ws_size,
                              hipStream_t stream) {
    const int*   d_index = (const int*)d_in[0];
    const int*   p_index = (const int*)d_in[1];
    const float* d_vecs  = (const float*)d_in[2];
    const float* p_emb   = (const float*)d_in[3];
    const float* d_ecfps = (const float*)d_in[4];
    const int*   d_eidx  = (const int*)d_in[5];
    const float* d_ew    = (const float*)d_in[6];
    const float* p_gos   = (const float*)d_in[7];
    const int*   p_eidx  = (const int*)d_in[8];
    const float* p_ew    = (const float*)d_in[9];
    const float* W_dg = (const float*)d_in[10];
    const float* b_dg = (const float*)d_in[11];
    const float* W_pg = (const float*)d_in[12];
    const float* b_pg = (const float*)d_in[13];
    const float* W_e1 = (const float*)d_in[14];
    // b_e1 cancels under BN (per-column shift invariance)
    const float* g_e1 = (const float*)d_in[16];
    const float* be_e1= (const float*)d_in[17];
    const float* W_e2 = (const float*)d_in[18];
    // b_e2 cancels under BN
    const float* g_e2 = (const float*)d_in[20];
    const float* be_e2= (const float*)d_in[21];
    const float* W_o1 = (const float*)d_in[22];
    const float* b_o1 = (const float*)d_in[23];   // pre-leaky: must apply
    const float* g_o  = (const float*)d_in[24];
    const float* be_o = (const float*)d_in[25];
    const float* W_o2 = (const float*)d_in[26];
    const float* b_o2 = (const float*)d_in[27];

    // ---- workspace layout ----
    char* w = (char*)d_ws;
    float*  agg   = (float*)w;   w += (size_t)BB * KP_P * 4;     // 46.1 MB (drug uses [BB,1024])
    bf16_t* aggb  = (bf16_t*)w;  w += (size_t)BB * KP_P * 2;     // 23.1 MB
    bf16_t* featb = (bf16_t*)w;  w += (size_t)BB * LDF * 2;      // 27.8 MB
    bf16_t* Wt_dg = (bf16_t*)w;  w += (size_t)1024 * 1024 * 2;
    bf16_t* Wt_pg = (bf16_t*)w;  w += (size_t)1024 * KP_P * 2;
    bf16_t* Wt_e1 = (bf16_t*)w;  w += (size_t)2048 * KF_P * 2;
    bf16_t* Wt_e2 = (bf16_t*)w;  w += (size_t)1024 * 2048 * 2;
    bf16_t* Wt_o1 = (bf16_t*)w;  w += (size_t)256 * 1024 * 2;
    float*  deg   = (float*)w;   w += (size_t)ND * 4;
    float*  dis   = (float*)w;   w += (size_t)ND * 4;
    int*    map   = (int*)w;     w += (size_t)ND * 4;
    float*  Z1    = (float*)w;   w += (size_t)BB * 2048 * 4;     // 33.6 MB
    bf16_t* Z1b   = (bf16_t*)w;  w += (size_t)BB * 2048 * 2;
    float*  Z2    = (float*)w;   w += (size_t)BB * 1024 * 4;
    bf16_t* feat2b= (bf16_t*)w;  w += (size_t)BB * 1024 * 2;
    float*  Z3    = (float*)w;   w += (size_t)BB * 256 * 4;
    float*  Z3n   = (float*)w;   w += (size_t)BB * 256 * 4;
    float*  stats = (float*)w;   w += 16384;

    float* y     = (float*)d_out;
    float* feat2 = (float*)d_out + BB;

    dim3 blk256(256);

    // ---- weight transposes ----
    transpose_convert<<<dim3(1024/32, 1024/32), blk256, 0, stream>>>(W_dg, Wt_dg, 1024, 1024, 1024);
    transpose_convert<<<dim3(1024/32, KP_P/32), blk256, 0, stream>>>(W_pg, Wt_pg, 2812, 1024, KP_P);
    transpose_convert<<<dim3(2048/32, KF_P/32), blk256, 0, stream>>>(W_e1, Wt_e1, 3372, 2048, KF_P);
    transpose_convert<<<dim3(1024/32, 2048/32), blk256, 0, stream>>>(W_e2, Wt_e2, 2048, 1024, 2048);
    transpose_convert<<<dim3(256/32, 1024/32), blk256, 0, stream>>>(W_o1, Wt_o1, 1024, 256, 1024);

    // ============ drug branch (F=1024) ============
    hipMemsetAsync(deg, 0, ND * sizeof(float), stream);
    hipMemsetAsync(map, 0xFF, ND * sizeof(int), stream);
    hipMemsetAsync(agg, 0, (size_t)BB * 1024 * sizeof(float), stream);

    deg_kernel<<<dim3((ED + 255) / 256), blk256, 0, stream>>>(d_eidx + ED, d_ew, deg, ED);
    dis_kernel<<<dim3((ND + 255) / 256), blk256, 0, stream>>>(deg, dis, ND);
    claim_kernel<<<dim3((BB + 255) / 256), blk256, 0, stream>>>(d_index, map, BB);
    scatter_in<<<dim3(ED), blk256, 0, stream>>>(d_eidx, d_eidx + ED, d_ew, dis, map, d_ecfps, agg, 1024);
    self_add<<<dim3(BB), blk256, 0, stream>>>(d_index, map, dis, d_ecfps, agg, 1024);
    {
        size_t tot = (size_t)BB * 1024;
        convert_pad<<<dim3((tot + 255) / 256), blk256, 0, stream>>>(agg, aggb, BB, 1024, 1024, tot);
    }
    gemm_bf16<<<dim3(1024/128, BB/128), blk256, 0, stream>>>(aggb, Wt_dg, nullptr, 0,
                                                             featb + 1324, LDF, b_dg, BB, 1024, 1024, 1);
    fix_dups<<<dim3(BB), blk256, 0, stream>>>(d_index, map, featb, 1324);

    // ============ protein branch (F=2812) ============
    hipMemsetAsync(deg, 0, NP * sizeof(float), stream);
    hipMemsetAsync(map, 0xFF, NP * sizeof(int), stream);
    hipMemsetAsync(agg, 0, (size_t)BB * 2812 * sizeof(float), stream);

    deg_kernel<<<dim3((EP + 255) / 256), blk256, 0, stream>>>(p_eidx + EP, p_ew, deg, EP);
    dis_kernel<<<dim3((NP + 255) / 256), blk256, 0, stream>>>(deg, dis, NP);
    claim_kernel<<<dim3((BB + 255) / 256), blk256, 0, stream>>>(p_index, map, BB);
    scatter_in<<<dim3(EP), blk256, 0, stream>>>(p_eidx, p_eidx + EP, p_ew, dis, map, p_gos, agg, 2812);
    self_add<<<dim3(BB), blk256, 0, stream>>>(p_index, map, dis, p_gos, agg, 2812);
    {
        size_t tot = (size_t)BB * KP_P;
        convert_pad<<<dim3((tot + 255) / 256), blk256, 0, stream>>>(agg, aggb, BB, 2812, KP_P, tot);
    }
    gemm_bf16<<<dim3(1024/128, BB/128), blk256, 0, stream>>>(aggb, Wt_pg, nullptr, 0,
                                                             featb + 2348, LDF, b_pg, BB, 1024, KP_P, 1);
    fix_dups<<<dim3(BB), blk256, 0, stream>>>(p_index, map, featb, 2348);

    // ============ dense concat ============
    {
        size_t t1 = (size_t)BB * 300, t2 = (size_t)BB * 1024;
        copy_cols_b<<<dim3((t1 + 255) / 256), blk256, 0, stream>>>(d_vecs, featb, 300, 0, t1);
        copy_cols_b<<<dim3((t2 + 255) / 256), blk256, 0, stream>>>(p_emb, featb, 1024, 300, t2);
    }

    // ============ e1: Z1 = featb @ W_e1; BN+leaky -> Z1b ============
    gemm_bf16<<<dim3(2048/128, BB/128), blk256, 0, stream>>>(featb, Wt_e1, Z1, 2048, nullptr, 0,
                                                             nullptr, BB, 2048, KF_P, 0);
    hipMemsetAsync(stats, 0, 2 * 2048 * sizeof(float), stream);
    bn_stats<<<dim3(2048/256, BB/256), blk256, 0, stream>>>(Z1, stats, 2048, 256);
    bn_apply<<<dim3(((size_t)BB*2048 + 255) / 256), blk256, 0, stream>>>(Z1, stats, g_e1, be_e1,
                                                                          nullptr, Z1b, 2048, 1, (size_t)BB*2048);

    // ============ e2: Z2 = Z1b @ W_e2; BN+leaky -> feat2 (f32 out) + feat2b ============
    gemm_bf16<<<dim3(1024/128, BB/128), blk256, 0, stream>>>(Z1b, Wt_e2, Z2, 1024, nullptr, 0,
                                                             nullptr, BB, 1024, 2048, 0);
    hipMemsetAsync(stats, 0, 2 * 1024 * sizeof(float), stream);
    bn_stats<<<dim3(1024/256, BB/256), blk256, 0, stream>>>(Z2, stats, 1024, 256);
    bn_apply<<<dim3(((size_t)BB*1024 + 255) / 256), blk256, 0, stream>>>(Z2, stats, g_e2, be_e2,
                                                                          feat2, feat2b, 1024, 1, (size_t)BB*1024);

    // ============ o1: Z3 = leaky(feat2b @ W_o1 + b_o1); BN -> Z3n; y ============
    gemm_bf16<<<dim3(256/128, BB/128), blk256, 0, stream>>>(feat2b, Wt_o1, Z3, 256, nullptr, 0,
                                                            b_o1, BB, 256, 1024, 1);
    hipMemsetAsync(stats, 0, 2 * 256 * sizeof(float), stream);
    bn_stats<<<dim3(1, BB/256), blk256, 0, stream>>>(Z3, stats, 256, 256);
    bn_apply<<<dim3(((size_t)BB*256 + 255) / 256), blk256, 0, stream>>>(Z3, stats, g_o, be_o,
                                                                         Z3n, nullptr, 256, 0, (size_t)BB*256);
    rowdot_kernel<<<dim3(BB/4), blk256, 0, stream>>>(Z3n, W_o2, b_o2, y, 256);
}